// Round 1
// baseline (901.182 us; speedup 1.0000x reference)
//
#include <hip/hip_runtime.h>
#include <math.h>

#define HID 128
#define NUMG 16
#define ZDIM 272
#define NCLS 21
#define LN_EPS 1e-5f

__device__ __forceinline__ float frcp(float x){ return __builtin_amdgcn_rcpf(x); }

// ---------------- preprocessing kernels ----------------

// Pack per-layer weights into Wpack[l][k][c] (k=0..127 over h, c=0..511 over
// [Af|As|Bf|Bs]) and Bias[l][c] = [bf|bs|0|0].
__global__ void pack_kernel(const float* __restrict__ Wf, const float* __restrict__ Ws,
                            const float* __restrict__ bf, const float* __restrict__ bs,
                            float* __restrict__ Wpack, float* __restrict__ Bias){
  int idx = blockIdx.x*256 + threadIdx.x;
  if (idx < 4*128*512){
    int l   = idx >> 16;       // /(128*512)
    int rem = idx & 65535;
    int k   = rem >> 9;        // /512
    int c   = rem & 511;
    const float* WfL = Wf + l*ZDIM*HID;
    const float* WsL = Ws + l*ZDIM*HID;
    float v;
    if      (c < 128) v = WfL[k*HID + c];
    else if (c < 256) v = WsL[k*HID + (c-128)];
    else if (c < 384) v = WfL[(128+k)*HID + (c-256)];
    else              v = WsL[(128+k)*HID + (c-384)];
    Wpack[idx] = v;
  }
  if (idx < 4*512){
    int ll = idx >> 9; int cc = idx & 511;
    float b = 0.f;
    if      (cc < 128) b = bf[ll*HID + cc];
    else if (cc < 256) b = bs[ll*HID + (cc-128)];
    Bias[idx] = b;
  }
}

// Gaussian RBF expansion of edge distances: rbf[e][k], k=0..15
__global__ void rbf_kernel(const float* __restrict__ dist, float* __restrict__ rbf, int E){
  int idx = blockIdx.x*256 + threadIdx.x;
  if (idx >= E*NUMG) return;
  int e = idx >> 4; int k = idx & 15;
  float d = dist[e];
  float t = d - (float)k * (8.0f/15.0f);
  rbf[idx] = __expf(-1.7578125f * t * t);   // COEFF = -0.5/(8/15)^2
}

// h = x @ W_node + b_node   ([N,6] @ [6,128])
__global__ void embed_kernel(const float* __restrict__ x, const float* __restrict__ Wn,
                             const float* __restrict__ bn, float* __restrict__ h, int N){
  int idx = blockIdx.x*256 + threadIdx.x;
  if (idx >= N*HID) return;
  int n = idx >> 7; int f = idx & 127;
  float acc = bn[f];
  const float* xr = x + n*6;
  #pragma unroll
  for (int k=0;k<6;k++) acc += xr[k]*Wn[k*HID+f];
  h[idx] = acc;
}

// CSR build: histogram of dst, exclusive scan, scatter edge ids.
__global__ void hist_kernel(const int* __restrict__ ei, int* __restrict__ deg, int E){
  int e = blockIdx.x*256 + threadIdx.x;
  if (e >= E) return;
  atomicAdd(&deg[ei[E + e]], 1);
}

__global__ void scan_kernel(const int* __restrict__ deg, int* __restrict__ rowptr,
                            int* __restrict__ cursor, int n){
  __shared__ int sm[1024];
  __shared__ int carry;
  int t = threadIdx.x;
  if (t == 0) carry = 0;
  __syncthreads();
  for (int base = 0; base < n; base += 1024){
    int i = base + t;
    int v = (i < n) ? deg[i] : 0;
    sm[t] = v; __syncthreads();
    #pragma unroll
    for (int off = 1; off < 1024; off <<= 1){
      int add = (t >= off) ? sm[t-off] : 0;
      __syncthreads();
      sm[t] += add;
      __syncthreads();
    }
    int excl = carry + sm[t] - v;
    if (i < n){ rowptr[i] = excl; cursor[i] = excl; }
    __syncthreads();
    if (t == 0) carry += sm[1023];
    __syncthreads();
  }
  if (t == 0) rowptr[n] = carry;
}

__global__ void scatter_kernel(const int* __restrict__ ei, int* __restrict__ cursor,
                               int* __restrict__ eidx, int E){
  int e = blockIdx.x*256 + threadIdx.x;
  if (e >= E) return;
  int dst = ei[E + e];
  int pos = atomicAdd(&cursor[dst], 1);
  eidx[pos] = e;
}

// ---------------- per-layer kernels ----------------

// [N,128] @ [128,512] -> Pdst ([Af|As]+bias), Psrc ([Bf|Bs]).
// Block: 256 threads, 16 rows; thread t owns cols t and t+256.
__launch_bounds__(256)
__global__ void node_gemm_kernel(const float* __restrict__ h, const float* __restrict__ Wp,
                                 const float* __restrict__ Bias, float* __restrict__ Pdst,
                                 float* __restrict__ Psrc, int N){
  __shared__ float lh[16*HID];
  int t  = threadIdx.x;
  int m0 = blockIdx.x*16;
  int rows = N - m0; if (rows > 16) rows = 16;
  for (int i = t; i < rows*HID; i += 256) lh[i] = h[m0*HID + i];
  __syncthreads();
  float acc0[16], acc1[16];
  #pragma unroll
  for (int r=0;r<16;r++){ acc0[r]=0.f; acc1[r]=0.f; }
  for (int k=0;k<HID;k+=4){
    float w0a = Wp[(k+0)*512 + t],       w0b = Wp[(k+1)*512 + t];
    float w0c = Wp[(k+2)*512 + t],       w0d = Wp[(k+3)*512 + t];
    float w1a = Wp[(k+0)*512 + t + 256], w1b = Wp[(k+1)*512 + t + 256];
    float w1c = Wp[(k+2)*512 + t + 256], w1d = Wp[(k+3)*512 + t + 256];
    #pragma unroll
    for (int r=0;r<16;r++){
      float4 a = *(const float4*)&lh[r*HID + k];
      acc0[r] += a.x*w0a + a.y*w0b + a.z*w0c + a.w*w0d;
      acc1[r] += a.x*w1a + a.y*w1b + a.z*w1c + a.w*w1d;
    }
  }
  float b0 = Bias[t], b1 = Bias[t+256];
  for (int r=0;r<rows;r++){
    Pdst[(size_t)(m0+r)*256 + t] = acc0[r] + b0;
    Psrc[(size_t)(m0+r)*256 + t] = acc1[r] + b1;
  }
}

// One block (128 threads) per destination node: loop its in-edges, compute
// gated message, accumulate in registers, single write. No atomics.
__launch_bounds__(128)
__global__ void agg_kernel(const float* __restrict__ Pdst, const float* __restrict__ Psrc,
                           const float* __restrict__ rbf, const int* __restrict__ ei,
                           const int* __restrict__ eidx, const int* __restrict__ rowptr,
                           const float* __restrict__ WfE, const float* __restrict__ WsE,
                           float* __restrict__ agg){
  int f    = threadIdx.x;
  int node = blockIdx.x;
  float wf[16], ws_[16];
  #pragma unroll
  for (int k=0;k<16;k++){ wf[k] = WfE[k*HID+f]; ws_[k] = WsE[k*HID+f]; }
  float af  = Pdst[(size_t)node*256 + f];
  float as_ = Pdst[(size_t)node*256 + 128 + f];
  float acc = 0.f;
  int beg = rowptr[node], end = rowptr[node+1];
  for (int j = beg; j < end; j++){
    int e   = eidx[j];
    int src = ei[e];
    const float4* r4 = (const float4*)(rbf + (size_t)e*16);
    float4 ra = r4[0], rb = r4[1], rc = r4[2], rd = r4[3];
    float bfv = Psrc[(size_t)src*256 + f];
    float bsv = Psrc[(size_t)src*256 + 128 + f];
    float ef = ra.x*wf[0] + ra.y*wf[1] + ra.z*wf[2] + ra.w*wf[3]
             + rb.x*wf[4] + rb.y*wf[5] + rb.z*wf[6] + rb.w*wf[7]
             + rc.x*wf[8] + rc.y*wf[9] + rc.z*wf[10]+ rc.w*wf[11]
             + rd.x*wf[12]+ rd.y*wf[13]+ rd.z*wf[14]+ rd.w*wf[15];
    float es = ra.x*ws_[0] + ra.y*ws_[1] + ra.z*ws_[2] + ra.w*ws_[3]
             + rb.x*ws_[4] + rb.y*ws_[5] + rb.z*ws_[6] + rb.w*ws_[7]
             + rc.x*ws_[8] + rc.y*ws_[9] + rc.z*ws_[10]+ rc.w*ws_[11]
             + rd.x*ws_[12]+ rd.y*ws_[13]+ rd.z*ws_[14]+ rd.w*ws_[15];
    float xf = af + bfv + ef;
    float xs = as_ + bsv + es;
    float g  = frcp(1.f + __expf(-xf));                          // sigmoid
    float sp = fmaxf(xs, 0.f) + __logf(1.f + __expf(-fabsf(xs))); // softplus
    acc += g * sp;
  }
  agg[(size_t)node*HID + f] = acc;
}

// Column sums / sums-of-squares for BatchNorm batch stats.
__global__ void bnstats_kernel(const float* __restrict__ agg, float* __restrict__ bnstat, int N){
  int f = threadIdx.x;  // 128
  float s = 0.f, q = 0.f;
  for (int r = blockIdx.x; r < N; r += gridDim.x){
    float v = agg[(size_t)r*HID + f];
    s += v; q += v*v;
  }
  atomicAdd(&bnstat[f],       s);
  atomicAdd(&bnstat[HID + f], q);
}

// Fused: BN-apply + residual + rowwise LayerNorm + ReLU + residual (in-place h).
// One wave per row; lane owns features (lane, lane+64).
__global__ void apply_kernel(const float* __restrict__ agg, float* __restrict__ h,
                             const float* __restrict__ bnstat,
                             const float* __restrict__ bng, const float* __restrict__ bnb,
                             const float* __restrict__ lng, const float* __restrict__ lnb,
                             int N, float invN){
  int wave = threadIdx.x >> 6, lane = threadIdx.x & 63;
  int row = blockIdx.x*4 + wave;
  if (row >= N) return;
  int f0 = lane, f1 = lane + 64;
  float mu0 = bnstat[f0]*invN,            mu1 = bnstat[f1]*invN;
  float v0  = bnstat[HID+f0]*invN - mu0*mu0;
  float v1  = bnstat[HID+f1]*invN - mu1*mu1;
  float a0 = agg[(size_t)row*HID + f0], a1 = agg[(size_t)row*HID + f1];
  float h0 = h[(size_t)row*HID + f0],   h1 = h[(size_t)row*HID + f1];
  float c0 = (a0-mu0)*rsqrtf(v0+LN_EPS)*bng[f0] + bnb[f0] + h0;
  float c1 = (a1-mu1)*rsqrtf(v1+LN_EPS)*bng[f1] + bnb[f1] + h1;
  float s = c0 + c1, q = c0*c0 + c1*c1;
  #pragma unroll
  for (int m=32;m;m>>=1){ s += __shfl_xor(s,m,64); q += __shfl_xor(q,m,64); }
  float mean = s*(1.0f/128.0f);
  float var  = q*(1.0f/128.0f) - mean*mean;
  float r = rsqrtf(var + LN_EPS);
  float l0 = (c0-mean)*r*lng[f0] + lnb[f0];
  float l1 = (c1-mean)*r*lng[f1] + lnb[f1];
  h[(size_t)row*HID + f0] = fmaxf(l0,0.f) + h0;
  h[(size_t)row*HID + f1] = fmaxf(l1,0.f) + h1;
}

// Final LayerNorm -> hn buffer.
__global__ void finalln_kernel(const float* __restrict__ h, float* __restrict__ hn,
                               const float* __restrict__ g, const float* __restrict__ b, int N){
  int wave = threadIdx.x >> 6, lane = threadIdx.x & 63;
  int row = blockIdx.x*4 + wave;
  if (row >= N) return;
  int f0 = lane, f1 = lane + 64;
  float c0 = h[(size_t)row*HID + f0], c1 = h[(size_t)row*HID + f1];
  float s = c0 + c1, q = c0*c0 + c1*c1;
  #pragma unroll
  for (int m=32;m;m>>=1){ s += __shfl_xor(s,m,64); q += __shfl_xor(q,m,64); }
  float mean = s*(1.0f/128.0f);
  float var  = q*(1.0f/128.0f) - mean*mean;
  float r = rsqrtf(var + LN_EPS);
  hn[(size_t)row*HID + f0] = (c0-mean)*r*g[f0] + b[f0];
  hn[(size_t)row*HID + f1] = (c1-mean)*r*g[f1] + b[f1];
}

// out = hn @ W_fc + b_fc   ([N,128] @ [128,21])
__global__ void fc_kernel(const float* __restrict__ hn, const float* __restrict__ Wfc,
                          const float* __restrict__ bfc, float* __restrict__ out, int N){
  __shared__ float wl[HID*NCLS];
  __shared__ float bl[NCLS];
  int t = threadIdx.x;
  for (int i = t; i < HID*NCLS; i += 256) wl[i] = Wfc[i];
  if (t < NCLS) bl[t] = bfc[t];
  __syncthreads();
  int idx = blockIdx.x*256 + t;
  if (idx >= N*NCLS) return;
  int n = idx / NCLS; int c = idx - n*NCLS;
  const float* hr = hn + (size_t)n*HID;
  float acc = bl[c];
  #pragma unroll 4
  for (int k=0;k<HID;k++) acc += hr[k]*wl[k*NCLS + c];
  out[idx] = acc;
}

// ---------------- host launcher ----------------

extern "C" void kernel_launch(void* const* d_in, const int* in_sizes, int n_in,
                              void* d_out, int out_size, void* d_ws, size_t ws_size,
                              hipStream_t stream){
  const float* x    = (const float*)d_in[0];
  const int*   ei   = (const int*)  d_in[1];
  const float* dist = (const float*)d_in[2];
  const float* Wn   = (const float*)d_in[3];
  const float* bn   = (const float*)d_in[4];
  const float* Wf   = (const float*)d_in[5];
  const float* bf   = (const float*)d_in[6];
  const float* Ws   = (const float*)d_in[7];
  const float* bs   = (const float*)d_in[8];
  const float* bng  = (const float*)d_in[9];
  const float* bnb  = (const float*)d_in[10];
  const float* lng  = (const float*)d_in[11];
  const float* lnb  = (const float*)d_in[12];
  const float* lnog = (const float*)d_in[13];
  const float* lnob = (const float*)d_in[14];
  const float* Wfc  = (const float*)d_in[15];
  const float* bfc  = (const float*)d_in[16];
  float* out = (float*)d_out;

  const int N = in_sizes[0] / 6;     // 20000
  const int E = in_sizes[2];         // 320000

  char* p = (char*)d_ws;
  auto alloc = [&](size_t bytes)->void*{
    void* r = (void*)p;
    p += (bytes + 255) & ~(size_t)255;
    return r;
  };
  float* h      = (float*)alloc((size_t)N*HID*4);    // 10.24 MB
  float* Pdst   = (float*)alloc((size_t)N*256*4);    // 20.48 MB
  float* Psrc   = (float*)alloc((size_t)N*256*4);    // 20.48 MB
  float* agg    = (float*)alloc((size_t)N*HID*4);    // 10.24 MB (reused as hn)
  float* rbfb   = (float*)alloc((size_t)E*NUMG*4);   // 20.48 MB
  float* Wpack  = (float*)alloc((size_t)4*128*512*4);// 1 MB
  float* Bias   = (float*)alloc((size_t)4*512*4);
  float* bnstat = (float*)alloc((size_t)256*4);
  int*   deg    = (int*)alloc((size_t)N*4);
  int*   rowptr = (int*)alloc((size_t)(N+1)*4);
  int*   cursor = (int*)alloc((size_t)N*4);
  int*   eidx   = (int*)alloc((size_t)E*4);          // 1.28 MB

  hipMemsetAsync(deg, 0, (size_t)N*4, stream);
  pack_kernel<<<1024, 256, 0, stream>>>(Wf, Ws, bf, bs, Wpack, Bias);
  rbf_kernel<<<(E*NUMG + 255)/256, 256, 0, stream>>>(dist, rbfb, E);
  embed_kernel<<<(N*HID + 255)/256, 256, 0, stream>>>(x, Wn, bn, h, N);
  hist_kernel<<<(E + 255)/256, 256, 0, stream>>>(ei, deg, E);
  scan_kernel<<<1, 1024, 0, stream>>>(deg, rowptr, cursor, N);
  scatter_kernel<<<(E + 255)/256, 256, 0, stream>>>(ei, cursor, eidx, E);

  float invN = 1.0f / (float)N;
  for (int l = 0; l < 4; l++){
    node_gemm_kernel<<<(N + 15)/16, 256, 0, stream>>>(
        h, Wpack + (size_t)l*128*512, Bias + (size_t)l*512, Pdst, Psrc, N);
    hipMemsetAsync(bnstat, 0, 256*4, stream);
    agg_kernel<<<N, 128, 0, stream>>>(
        Pdst, Psrc, rbfb, ei, eidx, rowptr,
        Wf + (size_t)l*ZDIM*HID + 256*HID,
        Ws + (size_t)l*ZDIM*HID + 256*HID, agg);
    bnstats_kernel<<<256, 128, 0, stream>>>(agg, bnstat, N);
    apply_kernel<<<(N + 3)/4, 256, 0, stream>>>(
        agg, h, bnstat, bng + l*HID, bnb + l*HID, lng + l*HID, lnb + l*HID, N, invN);
  }

  finalln_kernel<<<(N + 3)/4, 256, 0, stream>>>(h, agg, lnog, lnob, N);
  fc_kernel<<<(N*NCLS + 255)/256, 256, 0, stream>>>(agg, Wfc, bfc, out, N);
}

// Round 2
// 876.460 us; speedup vs baseline: 1.0282x; 1.0282x over previous
//
#include <hip/hip_runtime.h>
#include <hip/hip_fp16.h>
#include <math.h>

#define HID 128
#define NUMG 16
#define ZDIM 272
#define NCLS 21
#define LN_EPS 1e-5f

__device__ __forceinline__ float frcp(float x){ return __builtin_amdgcn_rcpf(x); }

// ---------------- preprocessing kernels ----------------

// Pack per-layer weights into Wpack[l][k][c] (k=0..127 over h, c=0..511 over
// [Af|As|Bf|Bs]) and Bias[l][c] = [bf|bs|0|0].
__global__ void pack_kernel(const float* __restrict__ Wf, const float* __restrict__ Ws,
                            const float* __restrict__ bf, const float* __restrict__ bs,
                            float* __restrict__ Wpack, float* __restrict__ Bias){
  int idx = blockIdx.x*256 + threadIdx.x;
  if (idx < 4*128*512){
    int l   = idx >> 16;
    int rem = idx & 65535;
    int k   = rem >> 9;
    int c   = rem & 511;
    const float* WfL = Wf + l*ZDIM*HID;
    const float* WsL = Ws + l*ZDIM*HID;
    float v;
    if      (c < 128) v = WfL[k*HID + c];
    else if (c < 256) v = WsL[k*HID + (c-128)];
    else if (c < 384) v = WfL[(128+k)*HID + (c-256)];
    else              v = WsL[(128+k)*HID + (c-384)];
    Wpack[idx] = v;
  }
  if (idx < 4*512){
    int ll = idx >> 9; int cc = idx & 511;
    float b = 0.f;
    if      (cc < 128) b = bf[ll*HID + cc];
    else if (cc < 256) b = bs[ll*HID + (cc-128)];
    Bias[idx] = b;
  }
}

// h = x @ W_node + b_node   ([N,6] @ [6,128])
__global__ void embed_kernel(const float* __restrict__ x, const float* __restrict__ Wn,
                             const float* __restrict__ bn, float* __restrict__ h, int N){
  int idx = blockIdx.x*256 + threadIdx.x;
  if (idx >= N*HID) return;
  int n = idx >> 7; int f = idx & 127;
  float acc = bn[f];
  const float* xr = x + n*6;
  #pragma unroll
  for (int k=0;k<6;k++) acc += xr[k]*Wn[k*HID+f];
  h[idx] = acc;
}

// ---------------- CSR build: hist -> 3-phase scan -> scatter ----------------

__global__ void hist_kernel(const int* __restrict__ ei, int* __restrict__ deg, int E){
  int e = blockIdx.x*256 + threadIdx.x;
  if (e >= E) return;
  atomicAdd(&deg[ei[E + e]], 1);
}

__global__ void scan_partial(const int* __restrict__ deg, int* __restrict__ bsum, int N){
  int t = threadIdx.x;
  int i = blockIdx.x*256 + t;
  int v = (i < N) ? deg[i] : 0;
  #pragma unroll
  for (int m=32;m;m>>=1) v += __shfl_xor(v, m, 64);
  __shared__ int ws[4];
  if ((t & 63) == 0) ws[t>>6] = v;
  __syncthreads();
  if (t == 0) bsum[blockIdx.x] = ws[0]+ws[1]+ws[2]+ws[3];
}

__global__ void scan_bsum(int* __restrict__ bsum, int nb){
  __shared__ int sm[256];
  int t = threadIdx.x;
  int v = (t < nb) ? bsum[t] : 0;
  sm[t] = v; __syncthreads();
  #pragma unroll
  for (int off=1; off<256; off<<=1){
    int add = (t >= off) ? sm[t-off] : 0;
    __syncthreads();
    sm[t] += add;
    __syncthreads();
  }
  if (t < nb) bsum[t] = sm[t] - v;   // exclusive prefix of block sums
}

__global__ void scan_write(const int* __restrict__ deg, const int* __restrict__ bsum,
                           int* __restrict__ rowptr, int* __restrict__ cursor, int N, int E){
  __shared__ int sm[256];
  int t = threadIdx.x;
  int i = blockIdx.x*256 + t;
  int v = (i < N) ? deg[i] : 0;
  sm[t] = v; __syncthreads();
  #pragma unroll
  for (int off=1; off<256; off<<=1){
    int add = (t >= off) ? sm[t-off] : 0;
    __syncthreads();
    sm[t] += add;
    __syncthreads();
  }
  if (i < N){
    int ex = bsum[blockIdx.x] + sm[t] - v;
    rowptr[i] = ex; cursor[i] = ex;
  }
  if (i == 0) rowptr[N] = E;
}

// Scatter edges into CSR order: src index and distance (no eidx indirection).
__global__ void scatter_kernel(const int* __restrict__ ei, const float* __restrict__ dist,
                               int* __restrict__ cursor, int* __restrict__ src_sorted,
                               float* __restrict__ dist_sorted, int E){
  int e = blockIdx.x*256 + threadIdx.x;
  if (e >= E) return;
  int dst = ei[E + e];
  int pos = atomicAdd(&cursor[dst], 1);
  src_sorted[pos]  = ei[e];
  dist_sorted[pos] = dist[e];
}

// ---------------- per-layer kernels ----------------

// [N,128] @ [128,512] -> Pdst2 = float2{Af+bf, As+bs}, Psrc2 = half2{Bf, Bs}.
// Thread t<128: cols (t, t+128); t>=128: cols (t+128, t+256).
__launch_bounds__(256)
__global__ void node_gemm_kernel(const float* __restrict__ h, const float* __restrict__ Wp,
                                 const float* __restrict__ Bias, float2* __restrict__ Pdst2,
                                 __half2* __restrict__ Psrc2, int N){
  __shared__ float lh[16*HID];
  int t  = threadIdx.x;
  int m0 = blockIdx.x*16;
  int rows = N - m0; if (rows > 16) rows = 16;
  for (int i = t; i < rows*HID; i += 256) lh[i] = h[m0*HID + i];
  __syncthreads();
  int col0 = t + (t & 128);    // t<128: t (Af|As pair); t>=128: 128+t (Bf|Bs pair)
  float acc0[16], acc1[16];
  #pragma unroll
  for (int r=0;r<16;r++){ acc0[r]=0.f; acc1[r]=0.f; }
  for (int k=0;k<HID;k+=4){
    float w0a = Wp[(k+0)*512 + col0],       w0b = Wp[(k+1)*512 + col0];
    float w0c = Wp[(k+2)*512 + col0],       w0d = Wp[(k+3)*512 + col0];
    float w1a = Wp[(k+0)*512 + col0 + 128], w1b = Wp[(k+1)*512 + col0 + 128];
    float w1c = Wp[(k+2)*512 + col0 + 128], w1d = Wp[(k+3)*512 + col0 + 128];
    #pragma unroll
    for (int r=0;r<16;r++){
      float4 a = *(const float4*)&lh[r*HID + k];
      acc0[r] += a.x*w0a + a.y*w0b + a.z*w0c + a.w*w0d;
      acc1[r] += a.x*w1a + a.y*w1b + a.z*w1c + a.w*w1d;
    }
  }
  float b0 = Bias[col0], b1 = Bias[col0 + 128];
  if (t < 128){
    for (int r=0;r<rows;r++)
      Pdst2[(m0+r)*HID + t] = make_float2(acc0[r] + b0, acc1[r] + b1);
  } else {
    int f = t - 128;
    for (int r=0;r<rows;r++)
      Psrc2[(m0+r)*HID + f] = __floats2half2_rn(acc0[r] + b0, acc1[r] + b1);
  }
}

// One block (128 threads) per destination node; 8-edge chunks staged in LDS
// (rbf computed cooperatively from sorted distances; src indices staged too).
#define CHUNK 8
__launch_bounds__(128)
__global__ void agg_kernel(const float2* __restrict__ Pdst2, const __half2* __restrict__ Psrc2,
                           const int* __restrict__ src_sorted, const float* __restrict__ dist_sorted,
                           const int* __restrict__ rowptr,
                           const float* __restrict__ WfE, const float* __restrict__ WsE,
                           float* __restrict__ agg){
  __shared__ __align__(16) float s_rbf[CHUNK][16];
  __shared__ int s_src[CHUNK];
  int f    = threadIdx.x;
  int node = blockIdx.x;
  float wf[16], ws_[16];
  #pragma unroll
  for (int k=0;k<16;k++){ wf[k] = WfE[k*HID+f]; ws_[k] = WsE[k*HID+f]; }
  float2 ad = Pdst2[node*HID + f];
  float af = ad.x, as_ = ad.y;
  float acc = 0.f;
  int beg = rowptr[node], end = rowptr[node+1];
  for (int j0 = beg; j0 < end; j0 += CHUNK){
    int cnt = end - j0; if (cnt > CHUNK) cnt = CHUNK;
    __syncthreads();
    if (f < cnt*16){
      int jj = f >> 4, k = f & 15;
      float d = dist_sorted[j0 + jj];
      float tt = d - (float)k * (8.0f/15.0f);
      s_rbf[jj][k] = __expf(-1.7578125f * tt * tt);
    }
    if (f < cnt) s_src[f] = src_sorted[j0 + f];
    __syncthreads();
    for (int jj = 0; jj < cnt; jj++){
      int src = s_src[jj];
      __half2 p = Psrc2[src*HID + f];
      float bfv = __low2float(p), bsv = __high2float(p);
      const float4* r4 = (const float4*)&s_rbf[jj][0];
      float4 ra = r4[0], rb = r4[1], rc = r4[2], rd = r4[3];
      float ef = ra.x*wf[0] + ra.y*wf[1] + ra.z*wf[2] + ra.w*wf[3]
               + rb.x*wf[4] + rb.y*wf[5] + rb.z*wf[6] + rb.w*wf[7]
               + rc.x*wf[8] + rc.y*wf[9] + rc.z*wf[10]+ rc.w*wf[11]
               + rd.x*wf[12]+ rd.y*wf[13]+ rd.z*wf[14]+ rd.w*wf[15];
      float es = ra.x*ws_[0] + ra.y*ws_[1] + ra.z*ws_[2] + ra.w*ws_[3]
               + rb.x*ws_[4] + rb.y*ws_[5] + rb.z*ws_[6] + rb.w*ws_[7]
               + rc.x*ws_[8] + rc.y*ws_[9] + rc.z*ws_[10]+ rc.w*ws_[11]
               + rd.x*ws_[12]+ rd.y*ws_[13]+ rd.z*ws_[14]+ rd.w*ws_[15];
      float xf = af + bfv + ef;
      float xs = as_ + bsv + es;
      float g  = frcp(1.f + __expf(-xf));                           // sigmoid
      float sp = fmaxf(xs, 0.f) + __logf(1.f + __expf(-fabsf(xs))); // softplus
      acc += g * sp;
    }
  }
  agg[node*HID + f] = acc;
}

// Column sums / sums-of-squares for BatchNorm batch stats.
__global__ void bnstats_kernel(const float* __restrict__ agg, float* __restrict__ bnstat, int N){
  int f = threadIdx.x;  // 128
  float s = 0.f, q = 0.f;
  for (int r = blockIdx.x; r < N; r += gridDim.x){
    float v = agg[r*HID + f];
    s += v; q += v*v;
  }
  atomicAdd(&bnstat[f],       s);
  atomicAdd(&bnstat[HID + f], q);
}

// Fused: BN-apply + residual + rowwise LayerNorm + ReLU + residual (in-place h).
__global__ void apply_kernel(const float* __restrict__ agg, float* __restrict__ h,
                             const float* __restrict__ bnstat,
                             const float* __restrict__ bng, const float* __restrict__ bnb,
                             const float* __restrict__ lng, const float* __restrict__ lnb,
                             int N, float invN){
  int wave = threadIdx.x >> 6, lane = threadIdx.x & 63;
  int row = blockIdx.x*4 + wave;
  if (row >= N) return;
  int f0 = lane, f1 = lane + 64;
  float mu0 = bnstat[f0]*invN,            mu1 = bnstat[f1]*invN;
  float v0  = bnstat[HID+f0]*invN - mu0*mu0;
  float v1  = bnstat[HID+f1]*invN - mu1*mu1;
  float a0 = agg[row*HID + f0], a1 = agg[row*HID + f1];
  float h0 = h[row*HID + f0],   h1 = h[row*HID + f1];
  float c0 = (a0-mu0)*rsqrtf(v0+LN_EPS)*bng[f0] + bnb[f0] + h0;
  float c1 = (a1-mu1)*rsqrtf(v1+LN_EPS)*bng[f1] + bnb[f1] + h1;
  float s = c0 + c1, q = c0*c0 + c1*c1;
  #pragma unroll
  for (int m=32;m;m>>=1){ s += __shfl_xor(s,m,64); q += __shfl_xor(q,m,64); }
  float mean = s*(1.0f/128.0f);
  float var  = q*(1.0f/128.0f) - mean*mean;
  float r = rsqrtf(var + LN_EPS);
  float l0 = (c0-mean)*r*lng[f0] + lnb[f0];
  float l1 = (c1-mean)*r*lng[f1] + lnb[f1];
  h[row*HID + f0] = fmaxf(l0,0.f) + h0;
  h[row*HID + f1] = fmaxf(l1,0.f) + h1;
}

// Final LayerNorm -> hn buffer.
__global__ void finalln_kernel(const float* __restrict__ h, float* __restrict__ hn,
                               const float* __restrict__ g, const float* __restrict__ b, int N){
  int wave = threadIdx.x >> 6, lane = threadIdx.x & 63;
  int row = blockIdx.x*4 + wave;
  if (row >= N) return;
  int f0 = lane, f1 = lane + 64;
  float c0 = h[row*HID + f0], c1 = h[row*HID + f1];
  float s = c0 + c1, q = c0*c0 + c1*c1;
  #pragma unroll
  for (int m=32;m;m>>=1){ s += __shfl_xor(s,m,64); q += __shfl_xor(q,m,64); }
  float mean = s*(1.0f/128.0f);
  float var  = q*(1.0f/128.0f) - mean*mean;
  float r = rsqrtf(var + LN_EPS);
  hn[row*HID + f0] = (c0-mean)*r*g[f0] + b[f0];
  hn[row*HID + f1] = (c1-mean)*r*g[f1] + b[f1];
}

// out = hn @ W_fc + b_fc   ([N,128] @ [128,21])
__global__ void fc_kernel(const float* __restrict__ hn, const float* __restrict__ Wfc,
                          const float* __restrict__ bfc, float* __restrict__ out, int N){
  __shared__ float wl[HID*NCLS];
  __shared__ float bl[NCLS];
  int t = threadIdx.x;
  for (int i = t; i < HID*NCLS; i += 256) wl[i] = Wfc[i];
  if (t < NCLS) bl[t] = bfc[t];
  __syncthreads();
  int idx = blockIdx.x*256 + t;
  if (idx >= N*NCLS) return;
  int n = idx / NCLS; int c = idx - n*NCLS;
  const float* hr = hn + n*HID;
  float acc = bl[c];
  #pragma unroll 4
  for (int k=0;k<HID;k++) acc += hr[k]*wl[k*NCLS + c];
  out[idx] = acc;
}

// ---------------- host launcher ----------------

extern "C" void kernel_launch(void* const* d_in, const int* in_sizes, int n_in,
                              void* d_out, int out_size, void* d_ws, size_t ws_size,
                              hipStream_t stream){
  const float* x    = (const float*)d_in[0];
  const int*   ei   = (const int*)  d_in[1];
  const float* dist = (const float*)d_in[2];
  const float* Wn   = (const float*)d_in[3];
  const float* bn   = (const float*)d_in[4];
  const float* Wf   = (const float*)d_in[5];
  const float* bf   = (const float*)d_in[6];
  const float* Ws   = (const float*)d_in[7];
  const float* bs   = (const float*)d_in[8];
  const float* bng  = (const float*)d_in[9];
  const float* bnb  = (const float*)d_in[10];
  const float* lng  = (const float*)d_in[11];
  const float* lnb  = (const float*)d_in[12];
  const float* lnog = (const float*)d_in[13];
  const float* lnob = (const float*)d_in[14];
  const float* Wfc  = (const float*)d_in[15];
  const float* bfc  = (const float*)d_in[16];
  float* out = (float*)d_out;

  const int N = in_sizes[0] / 6;     // 20000
  const int E = in_sizes[2];         // 320000
  const int NB = (N + 255)/256;      // scan blocks (79)

  char* p = (char*)d_ws;
  auto alloc = [&](size_t bytes)->void*{
    void* r = (void*)p;
    p += (bytes + 255) & ~(size_t)255;
    return r;
  };
  float*   h      = (float*)  alloc((size_t)N*HID*4);     // 10.24 MB
  float2*  Pdst2  = (float2*) alloc((size_t)N*HID*8);     // 20.48 MB
  __half2* Psrc2  = (__half2*)alloc((size_t)N*HID*4);     // 10.24 MB
  float*   agg    = (float*)  alloc((size_t)N*HID*4);     // 10.24 MB (reused as hn)
  float*   Wpack  = (float*)  alloc((size_t)4*128*512*4); // 1 MB
  float*   Bias   = (float*)  alloc((size_t)4*512*4);
  float*   bnstat = (float*)  alloc((size_t)256*4);
  int*     deg    = (int*)    alloc((size_t)N*4);
  int*     rowptr = (int*)    alloc((size_t)(N+1)*4);
  int*     cursor = (int*)    alloc((size_t)N*4);
  int*     bsum   = (int*)    alloc((size_t)NB*4);
  int*     srcs   = (int*)    alloc((size_t)E*4);         // 1.28 MB
  float*   dists  = (float*)  alloc((size_t)E*4);         // 1.28 MB

  hipMemsetAsync(deg, 0, (size_t)N*4, stream);
  pack_kernel<<<1024, 256, 0, stream>>>(Wf, Ws, bf, bs, Wpack, Bias);
  embed_kernel<<<(N*HID + 255)/256, 256, 0, stream>>>(x, Wn, bn, h, N);
  hist_kernel<<<(E + 255)/256, 256, 0, stream>>>(ei, deg, E);
  scan_partial<<<NB, 256, 0, stream>>>(deg, bsum, N);
  scan_bsum<<<1, 256, 0, stream>>>(bsum, NB);
  scan_write<<<NB, 256, 0, stream>>>(deg, bsum, rowptr, cursor, N, E);
  scatter_kernel<<<(E + 255)/256, 256, 0, stream>>>(ei, dist, cursor, srcs, dists, E);

  float invN = 1.0f / (float)N;
  for (int l = 0; l < 4; l++){
    node_gemm_kernel<<<(N + 15)/16, 256, 0, stream>>>(
        h, Wpack + (size_t)l*128*512, Bias + (size_t)l*512, Pdst2, Psrc2, N);
    hipMemsetAsync(bnstat, 0, 256*4, stream);
    agg_kernel<<<N, 128, 0, stream>>>(
        Pdst2, Psrc2, srcs, dists, rowptr,
        Wf + (size_t)l*ZDIM*HID + 256*HID,
        Ws + (size_t)l*ZDIM*HID + 256*HID, agg);
    bnstats_kernel<<<1024, 128, 0, stream>>>(agg, bnstat, N);
    apply_kernel<<<(N + 3)/4, 256, 0, stream>>>(
        agg, h, bnstat, bng + l*HID, bnb + l*HID, lng + l*HID, lnb + l*HID, N, invN);
  }

  finalln_kernel<<<(N + 3)/4, 256, 0, stream>>>(h, agg, lnog, lnob, N);
  fc_kernel<<<(N*NCLS + 255)/256, 256, 0, stream>>>(agg, Wfc, bfc, out, N);
}

// Round 3
// 702.481 us; speedup vs baseline: 1.2829x; 1.2477x over previous
//
#include <hip/hip_runtime.h>
#include <hip/hip_fp16.h>
#include <math.h>

#define HID 128
#define NUMG 16
#define ZDIM 272
#define NCLS 21
#define LN_EPS 1e-5f
#define DELTA (8.0f/15.0f)
#define RBFC  (-1.7578125f)   // -0.5/(8/15)^2

typedef _Float16 half8  __attribute__((ext_vector_type(8)));
typedef _Float16 half2t __attribute__((ext_vector_type(2)));
typedef float    floatx4 __attribute__((ext_vector_type(4)));

#if __has_builtin(__builtin_amdgcn_fdot2)
#define FDOT2(a,b,c) __builtin_amdgcn_fdot2((a),(b),(c),false)
#else
__device__ __forceinline__ float FDOT2(half2t a, half2t b, float c){
  return c + (float)a[0]*(float)b[0] + (float)a[1]*(float)b[1];
}
#endif

__device__ __forceinline__ float frcp(float x){ return __builtin_amdgcn_rcpf(x); }

// ---------------- preprocessing kernels ----------------

// Pack weights:
//  Wm16 [l][kb(4)][t(32)][lane(64)][j(8)] f16 — MFMA B-fragment order for the
//    node GEMM, columns interleaved c=2f+s (s=0:lin_f, 1:lin_s); c<256 dst rows
//    (W[0:128]), c>=256 src rows (W[128:256]).
//  Bias2 [l][256] fp32 interleaved (bf,bs) for the dst half.
//  WE2   [l][2][128][8] half2 — edge-RBF weights W[256:272] paired over k for fdot2.
__global__ void pack_kernel(const float* __restrict__ Wf, const float* __restrict__ Ws,
                            const float* __restrict__ bf, const float* __restrict__ bs,
                            _Float16* __restrict__ Wm16, float* __restrict__ Bias2,
                            half2t* __restrict__ WE2){
  int idx = blockIdx.x*256 + threadIdx.x;
  if (idx < 4*4*32*64*8){
    int l    = idx >> 16;
    int lane = (idx >> 3) & 63;
    int j    = idx & 7;
    int kb   = (idx >> 14) & 3;
    int t    = (idx >> 9) & 31;
    int k    = kb*32 + ((lane >> 4) << 3) + j;
    int c    = t*16 + (lane & 15);
    int row  = (c < 256) ? k : 128 + k;
    int cc   = (c < 256) ? c : c - 256;
    int f    = cc >> 1;
    const float* Wsel = ((c & 1) ? Ws : Wf) + l*ZDIM*HID;
    Wm16[idx] = (_Float16)Wsel[row*HID + f];
  }
  if (idx < 4*2*128*8){
    int k2 = idx & 7;
    int f  = (idx >> 3) & 127;
    int s  = (idx >> 10) & 1;
    int l  = (idx >> 11) & 3;
    const float* Wsel = (s ? Ws : Wf) + l*ZDIM*HID;
    half2t v;
    v[0] = (_Float16)Wsel[(256 + 2*k2    )*HID + f];
    v[1] = (_Float16)Wsel[(256 + 2*k2 + 1)*HID + f];
    WE2[idx] = v;
  }
  if (idx < 4*256){
    int l = idx >> 8; int c = idx & 255;
    Bias2[idx] = ((c & 1) ? bs : bf)[l*HID + (c >> 1)];
  }
}

// h = x @ W_node + b_node   ([N,6] @ [6,128])
__global__ void embed_kernel(const float* __restrict__ x, const float* __restrict__ Wn,
                             const float* __restrict__ bn, float* __restrict__ h, int N){
  int idx = blockIdx.x*256 + threadIdx.x;
  if (idx >= N*HID) return;
  int n = idx >> 7; int f = idx & 127;
  float acc = bn[f];
  const float* xr = x + n*6;
  #pragma unroll
  for (int k=0;k<6;k++) acc += xr[k]*Wn[k*HID+f];
  h[idx] = acc;
}

// ---------------- CSR build: hist -> 3-phase scan -> scatter ----------------

__global__ void hist_kernel(const int* __restrict__ ei, int* __restrict__ deg, int E){
  int e = blockIdx.x*256 + threadIdx.x;
  if (e >= E) return;
  atomicAdd(&deg[ei[E + e]], 1);
}

__global__ void scan_partial(const int* __restrict__ deg, int* __restrict__ bsum, int N){
  int t = threadIdx.x;
  int i = blockIdx.x*256 + t;
  int v = (i < N) ? deg[i] : 0;
  #pragma unroll
  for (int m=32;m;m>>=1) v += __shfl_xor(v, m, 64);
  __shared__ int ws[4];
  if ((t & 63) == 0) ws[t>>6] = v;
  __syncthreads();
  if (t == 0) bsum[blockIdx.x] = ws[0]+ws[1]+ws[2]+ws[3];
}

__global__ void scan_bsum(int* __restrict__ bsum, int nb){
  __shared__ int sm[256];
  int t = threadIdx.x;
  int v = (t < nb) ? bsum[t] : 0;
  sm[t] = v; __syncthreads();
  #pragma unroll
  for (int off=1; off<256; off<<=1){
    int add = (t >= off) ? sm[t-off] : 0;
    __syncthreads();
    sm[t] += add;
    __syncthreads();
  }
  if (t < nb) bsum[t] = sm[t] - v;
}

__global__ void scan_write(const int* __restrict__ deg, const int* __restrict__ bsum,
                           int* __restrict__ rowptr, int* __restrict__ cursor, int N, int E){
  __shared__ int sm[256];
  int t = threadIdx.x;
  int i = blockIdx.x*256 + t;
  int v = (i < N) ? deg[i] : 0;
  sm[t] = v; __syncthreads();
  #pragma unroll
  for (int off=1; off<256; off<<=1){
    int add = (t >= off) ? sm[t-off] : 0;
    __syncthreads();
    sm[t] += add;
    __syncthreads();
  }
  if (i < N){
    int ex = bsum[blockIdx.x] + sm[t] - v;
    rowptr[i] = ex; cursor[i] = ex;
  }
  if (i == 0) rowptr[N] = E;
}

__global__ void scatter_kernel(const int* __restrict__ ei, const float* __restrict__ dist,
                               int* __restrict__ cursor, int* __restrict__ src_sorted,
                               float* __restrict__ dist_sorted, int E){
  int e = blockIdx.x*256 + threadIdx.x;
  if (e >= E) return;
  int dst = ei[E + e];
  int pos = atomicAdd(&cursor[dst], 1);
  src_sorted[pos]  = ei[e];
  dist_sorted[pos] = dist[e];
}

// RBF expansion of sorted distances, packed half2 pairs: rbf16[e][k2]
__global__ void rbf16_kernel(const float* __restrict__ dist_sorted, half2t* __restrict__ rbf16, int E){
  int e = blockIdx.x*256 + threadIdx.x;
  if (e >= E) return;
  float d = dist_sorted[e];
  #pragma unroll
  for (int k2=0;k2<8;k2++){
    float t0 = d - (float)(2*k2)   * DELTA;
    float t1 = d - (float)(2*k2+1) * DELTA;
    half2t v;
    v[0] = (_Float16)__expf(RBFC*t0*t0);
    v[1] = (_Float16)__expf(RBFC*t1*t1);
    rbf16[e*8 + k2] = v;
  }
}

// ---------------- per-layer kernels ----------------

// MFMA node GEMM: [N,128]x[128,512] -> Pdst fp32 [N][256] interleaved (+bias),
// Psrc f16 [N][256] interleaved. Block=4 waves, M-tile=16 rows, wave w owns
// n-tiles w*8..w*8+7.
__launch_bounds__(256)
__global__ void node_gemm_kernel(const float* __restrict__ h, const _Float16* __restrict__ Wm,
                                 const float* __restrict__ Bias2, float* __restrict__ Pdst,
                                 _Float16* __restrict__ Psrc, int N){
  int lane = threadIdx.x & 63;
  int w    = threadIdx.x >> 6;
  int m0   = blockIdx.x * 16;
  int arow = m0 + (lane & 15);
  int kbase= (lane >> 4) * 8;
  floatx4 acc[8];
  #pragma unroll
  for (int t=0;t<8;t++) acc[t] = (floatx4){0.f,0.f,0.f,0.f};
  #pragma unroll
  for (int kb=0; kb<4; kb++){
    const float* ap = h + arow*HID + kb*32 + kbase;
    float4 a0 = *(const float4*)ap;
    float4 a1 = *(const float4*)(ap+4);
    half8 af;
    af[0]=(_Float16)a0.x; af[1]=(_Float16)a0.y; af[2]=(_Float16)a0.z; af[3]=(_Float16)a0.w;
    af[4]=(_Float16)a1.x; af[5]=(_Float16)a1.y; af[6]=(_Float16)a1.z; af[7]=(_Float16)a1.w;
    const _Float16* bp = Wm + ((kb*32 + w*8)*64 + lane)*8;
    #pragma unroll
    for (int t=0;t<8;t++){
      half8 b8 = *(const half8*)(bp + t*512);
      acc[t] = __builtin_amdgcn_mfma_f32_16x16x32_f16(af, b8, acc[t], 0,0,0);
    }
  }
  int quad = lane >> 4;
  int cl   = lane & 15;
  if (w < 2){
    #pragma unroll
    for (int t=0;t<8;t++){
      int c = (w*8+t)*16 + cl;
      float b2 = Bias2[c];
      #pragma unroll
      for (int r=0;r<4;r++)
        Pdst[(m0 + quad*4 + r)*256 + c] = acc[t][r] + b2;
    }
  } else {
    #pragma unroll
    for (int t=0;t<8;t++){
      int c = (w*8+t)*16 + cl - 256;
      #pragma unroll
      for (int r=0;r<4;r++)
        Psrc[(m0 + quad*4 + r)*256 + c] = (_Float16)acc[t][r];
    }
  }
}

// Aggregation: NPB nodes per 128-thread block; chunked LDS staging of src ids
// and packed rbf; fdot2 for the 16-wide RBF projection; gate+softplus+sum.
#define CHUNK 16
#define NPB 4
__launch_bounds__(128)
__global__ void agg_kernel(const float* __restrict__ Pdst, const _Float16* __restrict__ Psrc,
                           const int* __restrict__ srcs, const half2t* __restrict__ rbf16,
                           const int* __restrict__ rowptr,
                           const half2t* __restrict__ WEf, const half2t* __restrict__ WEs,
                           float* __restrict__ agg){
  __shared__ __align__(16) half2t s_rbf[CHUNK][8];
  __shared__ int s_src[CHUNK];
  int f = threadIdx.x;
  half2t wfh[8], wsh[8];
  *(uint4*)&wfh[0] = *(const uint4*)(WEf + f*8);
  *(uint4*)&wfh[4] = *(const uint4*)(WEf + f*8 + 4);
  *(uint4*)&wsh[0] = *(const uint4*)(WEs + f*8);
  *(uint4*)&wsh[4] = *(const uint4*)(WEs + f*8 + 4);
  for (int nn=0; nn<NPB; nn++){
    int node = blockIdx.x*NPB + nn;
    float2 ad = *(const float2*)(Pdst + node*256 + 2*f);
    float acc = 0.f;
    int beg = rowptr[node], end = rowptr[node+1];
    auto body = [&](int jj){
      int src = s_src[jj];
      half2t p2 = *(const half2t*)(Psrc + src*256 + 2*f);
      half2t rr[8];
      *(uint4*)&rr[0] = *(const uint4*)&s_rbf[jj][0];
      *(uint4*)&rr[4] = *(const uint4*)&s_rbf[jj][4];
      float ef = 0.f, es = 0.f;
      #pragma unroll
      for (int k2=0;k2<8;k2++){
        ef = FDOT2(rr[k2], wfh[k2], ef);
        es = FDOT2(rr[k2], wsh[k2], es);
      }
      float xf = ad.x + (float)p2[0] + ef;
      float xs = ad.y + (float)p2[1] + es;
      float g  = frcp(1.f + __expf(-xf));
      float sp = fmaxf(xs, 0.f) + __logf(1.f + __expf(-fabsf(xs)));
      acc += g * sp;
    };
    for (int j0=beg; j0<end; j0+=CHUNK){
      int cnt = end - j0; if (cnt > CHUNK) cnt = CHUNK;
      __syncthreads();
      if (f < cnt){
        s_src[f] = srcs[j0 + f];
        *(uint4*)&s_rbf[f][0] = *(const uint4*)(rbf16 + (j0 + f)*8);
        *(uint4*)&s_rbf[f][4] = *(const uint4*)(rbf16 + (j0 + f)*8 + 4);
      }
      __syncthreads();
      if (cnt == CHUNK){
        #pragma unroll 4
        for (int jj=0;jj<CHUNK;jj++) body(jj);
      } else {
        for (int jj=0;jj<cnt;jj++) body(jj);
      }
    }
    agg[node*HID + f] = acc;
  }
}

// Column sums / sums-of-squares for BatchNorm batch stats.
__global__ void bnstats_kernel(const float* __restrict__ agg, float* __restrict__ bnstat, int N){
  int f = threadIdx.x;  // 128
  float s = 0.f, q = 0.f;
  for (int r = blockIdx.x; r < N; r += gridDim.x){
    float v = agg[r*HID + f];
    s += v; q += v*v;
  }
  atomicAdd(&bnstat[f],       s);
  atomicAdd(&bnstat[HID + f], q);
}

// Fused: BN-apply + residual + rowwise LayerNorm + ReLU + residual (in-place h).
__global__ void apply_kernel(const float* __restrict__ agg, float* __restrict__ h,
                             const float* __restrict__ bnstat,
                             const float* __restrict__ bng, const float* __restrict__ bnb,
                             const float* __restrict__ lng, const float* __restrict__ lnb,
                             int N, float invN){
  int wave = threadIdx.x >> 6, lane = threadIdx.x & 63;
  int row = blockIdx.x*4 + wave;
  if (row >= N) return;
  int f0 = lane, f1 = lane + 64;
  float mu0 = bnstat[f0]*invN,            mu1 = bnstat[f1]*invN;
  float v0  = bnstat[HID+f0]*invN - mu0*mu0;
  float v1  = bnstat[HID+f1]*invN - mu1*mu1;
  float a0 = agg[row*HID + f0], a1 = agg[row*HID + f1];
  float h0 = h[row*HID + f0],   h1 = h[row*HID + f1];
  float c0 = (a0-mu0)*rsqrtf(v0+LN_EPS)*bng[f0] + bnb[f0] + h0;
  float c1 = (a1-mu1)*rsqrtf(v1+LN_EPS)*bng[f1] + bnb[f1] + h1;
  float s = c0 + c1, q = c0*c0 + c1*c1;
  #pragma unroll
  for (int m=32;m;m>>=1){ s += __shfl_xor(s,m,64); q += __shfl_xor(q,m,64); }
  float mean = s*(1.0f/128.0f);
  float var  = q*(1.0f/128.0f) - mean*mean;
  float r = rsqrtf(var + LN_EPS);
  float l0 = (c0-mean)*r*lng[f0] + lnb[f0];
  float l1 = (c1-mean)*r*lng[f1] + lnb[f1];
  h[row*HID + f0] = fmaxf(l0,0.f) + h0;
  h[row*HID + f1] = fmaxf(l1,0.f) + h1;
}

// Final LayerNorm -> hn buffer.
__global__ void finalln_kernel(const float* __restrict__ h, float* __restrict__ hn,
                               const float* __restrict__ g, const float* __restrict__ b, int N){
  int wave = threadIdx.x >> 6, lane = threadIdx.x & 63;
  int row = blockIdx.x*4 + wave;
  if (row >= N) return;
  int f0 = lane, f1 = lane + 64;
  float c0 = h[row*HID + f0], c1 = h[row*HID + f1];
  float s = c0 + c1, q = c0*c0 + c1*c1;
  #pragma unroll
  for (int m=32;m;m>>=1){ s += __shfl_xor(s,m,64); q += __shfl_xor(q,m,64); }
  float mean = s*(1.0f/128.0f);
  float var  = q*(1.0f/128.0f) - mean*mean;
  float r = rsqrtf(var + LN_EPS);
  hn[row*HID + f0] = (c0-mean)*r*g[f0] + b[f0];
  hn[row*HID + f1] = (c1-mean)*r*g[f1] + b[f1];
}

// out = hn @ W_fc + b_fc   ([N,128] @ [128,21])
__global__ void fc_kernel(const float* __restrict__ hn, const float* __restrict__ Wfc,
                          const float* __restrict__ bfc, float* __restrict__ out, int N){
  __shared__ float wl[HID*NCLS];
  __shared__ float bl[NCLS];
  int t = threadIdx.x;
  for (int i = t; i < HID*NCLS; i += 256) wl[i] = Wfc[i];
  if (t < NCLS) bl[t] = bfc[t];
  __syncthreads();
  int idx = blockIdx.x*256 + t;
  if (idx >= N*NCLS) return;
  int n = idx / NCLS; int c = idx - n*NCLS;
  const float* hr = hn + n*HID;
  float acc = bl[c];
  #pragma unroll 4
  for (int k=0;k<HID;k++) acc += hr[k]*wl[k*NCLS + c];
  out[idx] = acc;
}

// ---------------- host launcher ----------------

extern "C" void kernel_launch(void* const* d_in, const int* in_sizes, int n_in,
                              void* d_out, int out_size, void* d_ws, size_t ws_size,
                              hipStream_t stream){
  const float* x    = (const float*)d_in[0];
  const int*   ei   = (const int*)  d_in[1];
  const float* dist = (const float*)d_in[2];
  const float* Wn   = (const float*)d_in[3];
  const float* bn   = (const float*)d_in[4];
  const float* Wf   = (const float*)d_in[5];
  const float* bf   = (const float*)d_in[6];
  const float* Ws   = (const float*)d_in[7];
  const float* bs   = (const float*)d_in[8];
  const float* bng  = (const float*)d_in[9];
  const float* bnb  = (const float*)d_in[10];
  const float* lng  = (const float*)d_in[11];
  const float* lnb  = (const float*)d_in[12];
  const float* lnog = (const float*)d_in[13];
  const float* lnob = (const float*)d_in[14];
  const float* Wfc  = (const float*)d_in[15];
  const float* bfc  = (const float*)d_in[16];
  float* out = (float*)d_out;

  const int N = in_sizes[0] / 6;     // 20000
  const int E = in_sizes[2];         // 320000
  const int NB = (N + 255)/256;

  char* p = (char*)d_ws;
  auto alloc = [&](size_t bytes)->void*{
    void* r = (void*)p;
    p += (bytes + 255) & ~(size_t)255;
    return r;
  };
  float*     h      = (float*)    alloc((size_t)N*HID*4);      // 10.24 MB
  float*     Pdst   = (float*)    alloc((size_t)N*256*4);      // 20.48 MB
  _Float16*  Psrc   = (_Float16*) alloc((size_t)N*256*2);      // 10.24 MB
  float*     agg    = (float*)    alloc((size_t)N*HID*4);      // 10.24 MB
  _Float16*  Wm16   = (_Float16*) alloc((size_t)4*65536*2);    // 512 KB
  float*     Bias2  = (float*)    alloc((size_t)4*256*4);
  half2t*    WE2    = (half2t*)   alloc((size_t)4*2*128*8*4);  // 32 KB
  half2t*    rbf16  = (half2t*)   alloc((size_t)E*8*4);        // 10.24 MB
  float*     bnstat = (float*)    alloc((size_t)256*4);
  int*       deg    = (int*)      alloc((size_t)N*4);
  int*       rowptr = (int*)      alloc((size_t)(N+1)*4);
  int*       cursor = (int*)      alloc((size_t)N*4);
  int*       bsum   = (int*)      alloc((size_t)NB*4);
  int*       srcs   = (int*)      alloc((size_t)E*4);
  float*     dists  = (float*)    alloc((size_t)E*4);

  hipMemsetAsync(deg, 0, (size_t)N*4, stream);
  pack_kernel<<<1024, 256, 0, stream>>>(Wf, Ws, bf, bs, Wm16, Bias2, WE2);
  embed_kernel<<<(N*HID + 255)/256, 256, 0, stream>>>(x, Wn, bn, h, N);
  hist_kernel<<<(E + 255)/256, 256, 0, stream>>>(ei, deg, E);
  scan_partial<<<NB, 256, 0, stream>>>(deg, bsum, N);
  scan_bsum<<<1, 256, 0, stream>>>(bsum, NB);
  scan_write<<<NB, 256, 0, stream>>>(deg, bsum, rowptr, cursor, N, E);
  scatter_kernel<<<(E + 255)/256, 256, 0, stream>>>(ei, dist, cursor, srcs, dists, E);
  rbf16_kernel<<<(E + 255)/256, 256, 0, stream>>>(dists, rbf16, E);

  float invN = 1.0f / (float)N;
  for (int l = 0; l < 4; l++){
    node_gemm_kernel<<<N/16, 256, 0, stream>>>(
        h, Wm16 + (size_t)l*65536, Bias2 + (size_t)l*256, Pdst, Psrc, N);
    hipMemsetAsync(bnstat, 0, 256*4, stream);
    agg_kernel<<<N/NPB, 128, 0, stream>>>(
        Pdst, Psrc, srcs, rbf16, rowptr,
        WE2 + (size_t)(l*2 + 0)*128*8,
        WE2 + (size_t)(l*2 + 1)*128*8, agg);
    bnstats_kernel<<<1024, 128, 0, stream>>>(agg, bnstat, N);
    apply_kernel<<<(N + 3)/4, 256, 0, stream>>>(
        agg, h, bnstat, bng + l*HID, bnb + l*HID, lng + l*HID, lnb + l*HID, N, invN);
  }

  finalln_kernel<<<(N + 3)/4, 256, 0, stream>>>(h, agg, lnog, lnob, N);
  fc_kernel<<<(N*NCLS + 255)/256, 256, 0, stream>>>(agg, Wfc, bfc, out, N);
}

// Round 4
// 630.621 us; speedup vs baseline: 1.4290x; 1.1140x over previous
//
#include <hip/hip_runtime.h>
#include <hip/hip_fp16.h>
#include <math.h>

#define HID 128
#define NUMG 16
#define ZDIM 272
#define NCLS 21
#define LN_EPS 1e-5f
#define DELTA (8.0f/15.0f)
#define RBFC  (-1.7578125f)   // -0.5/(8/15)^2
#define NBINS 1024

typedef _Float16 half8  __attribute__((ext_vector_type(8)));
typedef _Float16 half4t __attribute__((ext_vector_type(4)));
typedef float    floatx4 __attribute__((ext_vector_type(4)));

__device__ __forceinline__ float frcp(float x){ return __builtin_amdgcn_rcpf(x); }

// ---------------- preprocessing kernels ----------------

// Wm16 [l][kb(4)][t(32)][lane(64)][j(8)] f16 — MFMA B-fragment order, columns
// interleaved c=2f+s (s=0:lin_f,1:lin_s); c<256 dst rows, c>=256 src rows.
// Bias2 [l][256] fp32 interleaved (bf,bs).
__global__ void pack_kernel(const float* __restrict__ Wf, const float* __restrict__ Ws,
                            const float* __restrict__ bf, const float* __restrict__ bs,
                            _Float16* __restrict__ Wm16, float* __restrict__ Bias2){
  int idx = blockIdx.x*256 + threadIdx.x;
  if (idx < 4*4*32*64*8){
    int l    = idx >> 16;
    int lane = (idx >> 3) & 63;
    int j    = idx & 7;
    int kb   = (idx >> 14) & 3;
    int t    = (idx >> 9) & 31;
    int k    = kb*32 + ((lane >> 4) << 3) + j;
    int c    = t*16 + (lane & 15);
    int row  = (c < 256) ? k : 128 + k;
    int cc   = (c < 256) ? c : c - 256;
    int f    = cc >> 1;
    const float* Wsel = ((c & 1) ? Ws : Wf) + l*ZDIM*HID;
    Wm16[idx] = (_Float16)Wsel[row*HID + f];
  }
  if (idx < 4*256){
    int l = idx >> 8; int c = idx & 255;
    Bias2[idx] = ((c & 1) ? bs : bf)[l*HID + (c >> 1)];
  }
}

// RBF-projection lookup table: T[l][bin][p], p packed: p=4f'+{0,1,2,3} =
// {(f',f),(f',s),(f'+64,f),(f'+64,s)}, f'=p>>2. T = sum_k rbf(d_bin,k)*W[256+k][feat].
__global__ void table_kernel(const float* __restrict__ Wf, const float* __restrict__ Ws,
                             _Float16* __restrict__ T){
  int idx = blockIdx.x*256 + threadIdx.x;   // 4*1024*256
  int l   = idx >> 18;
  int bin = (idx >> 8) & (NBINS-1);
  int p   = idx & 255;
  int s   = p & 1;
  int feat= (p >> 2) + ((p & 2) ? 64 : 0);
  const float* W = (s ? Ws : Wf) + l*ZDIM*HID;
  float d = 8.0f * (float)bin / (float)(NBINS-1);
  float acc = 0.f;
  #pragma unroll
  for (int k=0;k<16;k++){
    float t = d - (float)k * DELTA;
    acc += __expf(RBFC*t*t) * W[(256+k)*HID + feat];
  }
  T[idx] = (_Float16)acc;
}

// h = x @ W_node + b_node   ([N,6] @ [6,128])
__global__ void embed_kernel(const float* __restrict__ x, const float* __restrict__ Wn,
                             const float* __restrict__ bn, float* __restrict__ h, int N){
  int idx = blockIdx.x*256 + threadIdx.x;
  if (idx >= N*HID) return;
  int n = idx >> 7; int f = idx & 127;
  float acc = bn[f];
  const float* xr = x + n*6;
  #pragma unroll
  for (int k=0;k<6;k++) acc += xr[k]*Wn[k*HID+f];
  h[idx] = acc;
}

// ---------------- CSR build: hist -> 3-phase scan -> scatter ----------------

__global__ void hist_kernel(const int* __restrict__ ei, int* __restrict__ deg, int E){
  int e = blockIdx.x*256 + threadIdx.x;
  if (e >= E) return;
  atomicAdd(&deg[ei[E + e]], 1);
}

__global__ void scan_partial(const int* __restrict__ deg, int* __restrict__ bsum, int N){
  int t = threadIdx.x;
  int i = blockIdx.x*256 + t;
  int v = (i < N) ? deg[i] : 0;
  #pragma unroll
  for (int m=32;m;m>>=1) v += __shfl_xor(v, m, 64);
  __shared__ int ws[4];
  if ((t & 63) == 0) ws[t>>6] = v;
  __syncthreads();
  if (t == 0) bsum[blockIdx.x] = ws[0]+ws[1]+ws[2]+ws[3];
}

__global__ void scan_bsum(int* __restrict__ bsum, int nb){
  __shared__ int sm[256];
  int t = threadIdx.x;
  int v = (t < nb) ? bsum[t] : 0;
  sm[t] = v; __syncthreads();
  #pragma unroll
  for (int off=1; off<256; off<<=1){
    int add = (t >= off) ? sm[t-off] : 0;
    __syncthreads();
    sm[t] += add;
    __syncthreads();
  }
  if (t < nb) bsum[t] = sm[t] - v;
}

__global__ void scan_write(const int* __restrict__ deg, const int* __restrict__ bsum,
                           int* __restrict__ rowptr, int* __restrict__ cursor, int N, int E){
  __shared__ int sm[256];
  int t = threadIdx.x;
  int i = blockIdx.x*256 + t;
  int v = (i < N) ? deg[i] : 0;
  sm[t] = v; __syncthreads();
  #pragma unroll
  for (int off=1; off<256; off<<=1){
    int add = (t >= off) ? sm[t-off] : 0;
    __syncthreads();
    sm[t] += add;
    __syncthreads();
  }
  if (i < N){
    int ex = bsum[blockIdx.x] + sm[t] - v;
    rowptr[i] = ex; cursor[i] = ex;
  }
  if (i == 0) rowptr[N] = E;
}

// Scatter edges into CSR order as packed {src*256, bin<<16 | f16(lerp_w)}.
__global__ void scatter_kernel(const int* __restrict__ ei, const float* __restrict__ dist,
                               int* __restrict__ cursor, int2* __restrict__ edata, int E){
  int e = blockIdx.x*256 + threadIdx.x;
  if (e >= E) return;
  int dst = ei[E + e];
  int pos = atomicAdd(&cursor[dst], 1);
  float d = dist[e];
  float xx = d * ((float)(NBINS-1) / 8.0f);
  int b = (int)xx;
  if (b > NBINS-2) b = NBINS-2;
  if (b < 0) b = 0;
  _Float16 hw = (_Float16)(xx - (float)b);
  unsigned short hb; __builtin_memcpy(&hb, &hw, 2);
  edata[pos] = make_int2(ei[e]*256, (b << 16) | (int)hb);
}

// ---------------- per-layer kernels ----------------

// MFMA node GEMM: [N,128]x[128,512] -> Pdst fp32 [N][64][4] packed (+bias),
// Psrc f16 [N][64][4] packed. Packed p = 4*f' + {f_lo, s_lo, f_hi, s_hi}.
__launch_bounds__(256)
__global__ void node_gemm_kernel(const float* __restrict__ h, const _Float16* __restrict__ Wm,
                                 const float* __restrict__ Bias2, float* __restrict__ Pdst,
                                 _Float16* __restrict__ Psrc, int N){
  int lane = threadIdx.x & 63;
  int w    = threadIdx.x >> 6;
  int m0   = blockIdx.x * 16;
  int arow = m0 + (lane & 15);
  int kbase= (lane >> 4) * 8;
  floatx4 acc[8];
  #pragma unroll
  for (int t=0;t<8;t++) acc[t] = (floatx4){0.f,0.f,0.f,0.f};
  #pragma unroll
  for (int kb=0; kb<4; kb++){
    const float* ap = h + arow*HID + kb*32 + kbase;
    float4 a0 = *(const float4*)ap;
    float4 a1 = *(const float4*)(ap+4);
    half8 af;
    af[0]=(_Float16)a0.x; af[1]=(_Float16)a0.y; af[2]=(_Float16)a0.z; af[3]=(_Float16)a0.w;
    af[4]=(_Float16)a1.x; af[5]=(_Float16)a1.y; af[6]=(_Float16)a1.z; af[7]=(_Float16)a1.w;
    const _Float16* bp = Wm + ((kb*32 + w*8)*64 + lane)*8;
    #pragma unroll
    for (int t=0;t<8;t++){
      half8 b8 = *(const half8*)(bp + t*512);
      acc[t] = __builtin_amdgcn_mfma_f32_16x16x32_f16(af, b8, acc[t], 0,0,0);
    }
  }
  int quad = lane >> 4;
  int cl   = lane & 15;
  int hi2  = (w & 1) ? 2 : 0;       // upper-64 feature half?
  if (w < 2){
    #pragma unroll
    for (int t=0;t<8;t++){
      int cp = t*16 + cl;                       // 0..127 within half
      int c  = (w&1)*128 + cp;                  // Bias2 index
      int p  = ((cp >> 1) << 2) + hi2 + (cp & 1);
      float b2 = Bias2[c];
      #pragma unroll
      for (int r=0;r<4;r++)
        Pdst[(m0 + quad*4 + r)*256 + p] = acc[t][r] + b2;
    }
  } else {
    #pragma unroll
    for (int t=0;t<8;t++){
      int cp = (w-2)*0 + t*16 + cl;             // 0..127 within half (w=2 lo, w=3 hi)
      int p  = ((cp >> 1) << 2) + hi2 + (cp & 1);
      #pragma unroll
      for (int r=0;r<4;r++)
        Psrc[(m0 + quad*4 + r)*256 + p] = (_Float16)acc[t][r];
    }
  }
}

// Aggregation: one wave per node-group (NPB nodes sequential), lane owns
// features (f', f'+64). Table-lerp for the RBF projection. No LDS, no barriers.
#define NPB 4
__launch_bounds__(256)
__global__ void agg_kernel(const float* __restrict__ Pdst, const _Float16* __restrict__ Psrc,
                           const int2* __restrict__ edata, const int* __restrict__ rowptr,
                           const _Float16* __restrict__ T,
                           float2* __restrict__ agg2, float* __restrict__ bnstat){
  if (blockIdx.x == 0) bnstat[threadIdx.x] = 0.f;   // zero stats for bnstats_kernel
  int lane = threadIdx.x & 63;
  int w    = threadIdx.x >> 6;
  int l4   = lane * 4;
  int node0 = (blockIdx.x*4 + w) * NPB;
  for (int nn=0; nn<NPB; nn++){
    int node = node0 + nn;
    float4 ad = *(const float4*)(Pdst + node*256 + l4);
    float acc0 = 0.f, acc1 = 0.f;
    int beg = rowptr[node], end = rowptr[node+1];
    #pragma unroll 4
    for (int j=beg; j<end; j++){
      int2 ed = edata[j];
      half4t p4 = *(const half4t*)(Psrc + ed.x + l4);
      int bin = ((unsigned)ed.y) >> 16;
      unsigned short hb = (unsigned short)(ed.y & 0xffff);
      _Float16 hw; __builtin_memcpy(&hw, &hb, 2);
      const _Float16* tp = T + bin*256 + l4;
      half4t t0 = *(const half4t*)tp;
      half4t t1 = *(const half4t*)(tp + 256);
      half4t res = t0 + (t1 - t0) * hw;
      float xf0 = ad.x + (float)p4[0] + (float)res[0];
      float xs0 = ad.y + (float)p4[1] + (float)res[1];
      float xf1 = ad.z + (float)p4[2] + (float)res[2];
      float xs1 = ad.w + (float)p4[3] + (float)res[3];
      float g0  = frcp(1.f + __expf(-xf0));
      float sp0 = fmaxf(xs0, 0.f) + __logf(1.f + __expf(-fabsf(xs0)));
      float g1  = frcp(1.f + __expf(-xf1));
      float sp1 = fmaxf(xs1, 0.f) + __logf(1.f + __expf(-fabsf(xs1)));
      acc0 += g0 * sp0;
      acc1 += g1 * sp1;
    }
    agg2[node*64 + lane] = make_float2(acc0, acc1);
  }
}

// Column sums / sums-of-squares for BatchNorm batch stats (packed-col layout).
__global__ void bnstats_kernel(const float* __restrict__ agg, float* __restrict__ bnstat, int N){
  int f = threadIdx.x;  // 128 packed cols
  float s = 0.f, q = 0.f;
  for (int r = blockIdx.x; r < N; r += gridDim.x){
    float v = agg[r*HID + f];
    s += v; q += v*v;
  }
  atomicAdd(&bnstat[f],       s);
  atomicAdd(&bnstat[HID + f], q);
}

// Fused: BN-apply + residual + rowwise LayerNorm + ReLU + residual (in-place h).
// agg2 packed: lane holds features (lane, lane+64); stats in packed cols (2lane, 2lane+1).
__global__ void apply_kernel(const float2* __restrict__ agg2, float* __restrict__ h,
                             const float* __restrict__ bnstat,
                             const float* __restrict__ bng, const float* __restrict__ bnb,
                             const float* __restrict__ lng, const float* __restrict__ lnb,
                             int N, float invN){
  int wave = threadIdx.x >> 6, lane = threadIdx.x & 63;
  int row = blockIdx.x*4 + wave;
  if (row >= N) return;
  int f0 = lane, f1 = lane + 64;
  float mu0 = bnstat[2*lane]*invN,   mu1 = bnstat[2*lane+1]*invN;
  float v0  = bnstat[HID+2*lane]*invN   - mu0*mu0;
  float v1  = bnstat[HID+2*lane+1]*invN - mu1*mu1;
  float2 a  = agg2[row*64 + lane];
  float h0 = h[row*HID + f0],   h1 = h[row*HID + f1];
  float c0 = (a.x-mu0)*rsqrtf(v0+LN_EPS)*bng[f0] + bnb[f0] + h0;
  float c1 = (a.y-mu1)*rsqrtf(v1+LN_EPS)*bng[f1] + bnb[f1] + h1;
  float s = c0 + c1, q = c0*c0 + c1*c1;
  #pragma unroll
  for (int m=32;m;m>>=1){ s += __shfl_xor(s,m,64); q += __shfl_xor(q,m,64); }
  float mean = s*(1.0f/128.0f);
  float var  = q*(1.0f/128.0f) - mean*mean;
  float r = rsqrtf(var + LN_EPS);
  float l0 = (c0-mean)*r*lng[f0] + lnb[f0];
  float l1 = (c1-mean)*r*lng[f1] + lnb[f1];
  h[row*HID + f0] = fmaxf(l0,0.f) + h0;
  h[row*HID + f1] = fmaxf(l1,0.f) + h1;
}

// Final LayerNorm -> hn buffer.
__global__ void finalln_kernel(const float* __restrict__ h, float* __restrict__ hn,
                               const float* __restrict__ g, const float* __restrict__ b, int N){
  int wave = threadIdx.x >> 6, lane = threadIdx.x & 63;
  int row = blockIdx.x*4 + wave;
  if (row >= N) return;
  int f0 = lane, f1 = lane + 64;
  float c0 = h[row*HID + f0], c1 = h[row*HID + f1];
  float s = c0 + c1, q = c0*c0 + c1*c1;
  #pragma unroll
  for (int m=32;m;m>>=1){ s += __shfl_xor(s,m,64); q += __shfl_xor(q,m,64); }
  float mean = s*(1.0f/128.0f);
  float var  = q*(1.0f/128.0f) - mean*mean;
  float r = rsqrtf(var + LN_EPS);
  hn[row*HID + f0] = (c0-mean)*r*g[f0] + b[f0];
  hn[row*HID + f1] = (c1-mean)*r*g[f1] + b[f1];
}

// out = hn @ W_fc + b_fc   ([N,128] @ [128,21])
__global__ void fc_kernel(const float* __restrict__ hn, const float* __restrict__ Wfc,
                          const float* __restrict__ bfc, float* __restrict__ out, int N){
  __shared__ float wl[HID*NCLS];
  __shared__ float bl[NCLS];
  int t = threadIdx.x;
  for (int i = t; i < HID*NCLS; i += 256) wl[i] = Wfc[i];
  if (t < NCLS) bl[t] = bfc[t];
  __syncthreads();
  int idx = blockIdx.x*256 + t;
  if (idx >= N*NCLS) return;
  int n = idx / NCLS; int c = idx - n*NCLS;
  const float* hr = hn + n*HID;
  float acc = bl[c];
  #pragma unroll 4
  for (int k=0;k<HID;k++) acc += hr[k]*wl[k*NCLS + c];
  out[idx] = acc;
}

// ---------------- host launcher ----------------

extern "C" void kernel_launch(void* const* d_in, const int* in_sizes, int n_in,
                              void* d_out, int out_size, void* d_ws, size_t ws_size,
                              hipStream_t stream){
  const float* x    = (const float*)d_in[0];
  const int*   ei   = (const int*)  d_in[1];
  const float* dist = (const float*)d_in[2];
  const float* Wn   = (const float*)d_in[3];
  const float* bn   = (const float*)d_in[4];
  const float* Wf   = (const float*)d_in[5];
  const float* bf   = (const float*)d_in[6];
  const float* Ws   = (const float*)d_in[7];
  const float* bs   = (const float*)d_in[8];
  const float* bng  = (const float*)d_in[9];
  const float* bnb  = (const float*)d_in[10];
  const float* lng  = (const float*)d_in[11];
  const float* lnb  = (const float*)d_in[12];
  const float* lnog = (const float*)d_in[13];
  const float* lnob = (const float*)d_in[14];
  const float* Wfc  = (const float*)d_in[15];
  const float* bfc  = (const float*)d_in[16];
  float* out = (float*)d_out;

  const int N = in_sizes[0] / 6;     // 20000
  const int E = in_sizes[2];         // 320000
  const int NB = (N + 255)/256;

  char* p = (char*)d_ws;
  auto alloc = [&](size_t bytes)->void*{
    void* r = (void*)p;
    p += (bytes + 255) & ~(size_t)255;
    return r;
  };
  float*     h      = (float*)    alloc((size_t)N*HID*4);      // 10.24 MB
  float*     Pdst   = (float*)    alloc((size_t)N*256*4);      // 20.48 MB
  _Float16*  Psrc   = (_Float16*) alloc((size_t)N*256*2);      // 10.24 MB
  float2*    agg2   = (float2*)   alloc((size_t)N*64*8);       // 10.24 MB
  _Float16*  Wm16   = (_Float16*) alloc((size_t)4*65536*2);    // 512 KB
  float*     Bias2  = (float*)    alloc((size_t)4*256*4);
  _Float16*  T      = (_Float16*) alloc((size_t)4*NBINS*256*2);// 2 MB
  float*     bnstat = (float*)    alloc((size_t)256*4);
  int*       deg    = (int*)      alloc((size_t)N*4);
  int*       rowptr = (int*)      alloc((size_t)(N+1)*4);
  int*       cursor = (int*)      alloc((size_t)N*4);
  int*       bsum   = (int*)      alloc((size_t)NB*4);
  int2*      edata  = (int2*)     alloc((size_t)E*8);          // 2.56 MB

  hipMemsetAsync(deg, 0, (size_t)N*4, stream);
  pack_kernel<<<1024, 256, 0, stream>>>(Wf, Ws, bf, bs, Wm16, Bias2);
  table_kernel<<<4096, 256, 0, stream>>>(Wf, Ws, T);
  embed_kernel<<<(N*HID + 255)/256, 256, 0, stream>>>(x, Wn, bn, h, N);
  hist_kernel<<<(E + 255)/256, 256, 0, stream>>>(ei, deg, E);
  scan_partial<<<NB, 256, 0, stream>>>(deg, bsum, N);
  scan_bsum<<<1, 256, 0, stream>>>(bsum, NB);
  scan_write<<<NB, 256, 0, stream>>>(deg, bsum, rowptr, cursor, N, E);
  scatter_kernel<<<(E + 255)/256, 256, 0, stream>>>(ei, dist, cursor, edata, E);

  float invN = 1.0f / (float)N;
  for (int l = 0; l < 4; l++){
    node_gemm_kernel<<<N/16, 256, 0, stream>>>(
        h, Wm16 + (size_t)l*65536, Bias2 + (size_t)l*256, Pdst, Psrc, N);
    agg_kernel<<<N/(4*NPB), 256, 0, stream>>>(
        Pdst, Psrc, edata, rowptr, T + (size_t)l*NBINS*256, agg2, bnstat);
    bnstats_kernel<<<1024, 128, 0, stream>>>((const float*)agg2, bnstat, N);
    apply_kernel<<<(N + 3)/4, 256, 0, stream>>>(
        agg2, h, bnstat, bng + l*HID, bnb + l*HID, lng + l*HID, lnb + l*HID, N, invN);
  }

  finalln_kernel<<<(N + 3)/4, 256, 0, stream>>>(h, agg2 ? (float*)agg2 : nullptr, lnog, lnob, N);
  fc_kernel<<<(N*NCLS + 255)/256, 256, 0, stream>>>((const float*)agg2, Wfc, bfc, out, N);
}

// Round 5
// 586.191 us; speedup vs baseline: 1.5374x; 1.0758x over previous
//
#include <hip/hip_runtime.h>
#include <hip/hip_fp16.h>
#include <math.h>

#define HID 128
#define NUMG 16
#define ZDIM 272
#define NCLS 21
#define LN_EPS 1e-5f
#define DELTA (8.0f/15.0f)
#define RBFC  (-1.7578125f)   // -0.5/(8/15)^2
#define NBINS 1024

typedef _Float16 half8  __attribute__((ext_vector_type(8)));
typedef _Float16 half4t __attribute__((ext_vector_type(4)));
typedef float    floatx4 __attribute__((ext_vector_type(4)));

__device__ __forceinline__ float frcp(float x){ return __builtin_amdgcn_rcpf(x); }

// ---------------- preprocessing kernels ----------------

// Wm16 [l][kb(4)][t(32)][lane(64)][j(8)] f16 — MFMA B-fragment order, columns
// interleaved c=2f+s (s=0:lin_f,1:lin_s); c<256 dst rows, c>=256 src rows.
// Bias2 [l][256] fp32 interleaved (bf,bs).
__global__ void pack_kernel(const float* __restrict__ Wf, const float* __restrict__ Ws,
                            const float* __restrict__ bf, const float* __restrict__ bs,
                            _Float16* __restrict__ Wm16, float* __restrict__ Bias2){
  int idx = blockIdx.x*256 + threadIdx.x;
  if (idx < 4*4*32*64*8){
    int l    = idx >> 16;
    int lane = (idx >> 3) & 63;
    int j    = idx & 7;
    int kb   = (idx >> 14) & 3;
    int t    = (idx >> 9) & 3;
    t = (idx >> 9) & 31;
    int k    = kb*32 + ((lane >> 4) << 3) + j;
    int c    = t*16 + (lane & 15);
    int row  = (c < 256) ? k : 128 + k;
    int cc   = (c < 256) ? c : c - 256;
    int f    = cc >> 1;
    const float* Wsel = ((c & 1) ? Ws : Wf) + l*ZDIM*HID;
    Wm16[idx] = (_Float16)Wsel[row*HID + f];
  }
  if (idx < 4*256){
    int l = idx >> 8; int c = idx & 255;
    Bias2[idx] = ((c & 1) ? bs : bf)[l*HID + (c >> 1)];
  }
}

// RBF-projection lookup table: T[l][bin][p], p packed = 4f'+{f_lo,s_lo,f_hi,s_hi}.
// Block b: l=b>>6, bins [ (b&63)*16, +16 ). LDS-staged W slice and per-bin RBF.
__launch_bounds__(256)
__global__ void table_kernel(const float* __restrict__ Wf, const float* __restrict__ Ws,
                             _Float16* __restrict__ T){
  __shared__ float sW[16][256];
  __shared__ float sR[16][16];
  int l    = blockIdx.x >> 6;
  int bin0 = (blockIdx.x & 63) * 16;
  int t = threadIdx.x;
  for (int i = t; i < 16*256; i += 256){
    int k = i >> 8; int p = i & 255;
    int s = p & 1; int feat = (p >> 2) + ((p & 2) ? 64 : 0);
    const float* W = (s ? Ws : Wf) + l*ZDIM*HID;
    sW[k][p] = W[(256+k)*HID + feat];
  }
  {
    int bi = t >> 4; int k = t & 15;
    float d = 8.0f * (float)(bin0 + bi) / (float)(NBINS-1);
    float x = d - (float)k * DELTA;
    sR[bi][k] = __expf(RBFC*x*x);
  }
  __syncthreads();
  for (int i = t; i < 16*256; i += 256){
    int bi = i >> 8; int p = i & 255;
    float acc = 0.f;
    #pragma unroll
    for (int k=0;k<16;k++) acc += sR[bi][k]*sW[k][p];
    T[((size_t)l*NBINS + bin0 + bi)*256 + p] = (_Float16)acc;
  }
}

// h = x @ W_node + b_node   ([N,6] @ [6,128])
__global__ void embed_kernel(const float* __restrict__ x, const float* __restrict__ Wn,
                             const float* __restrict__ bn, float* __restrict__ h, int N){
  int idx = blockIdx.x*256 + threadIdx.x;
  if (idx >= N*HID) return;
  int n = idx >> 7; int f = idx & 127;
  float acc = bn[f];
  const float* xr = x + n*6;
  #pragma unroll
  for (int k=0;k<6;k++) acc += xr[k]*Wn[k*HID+f];
  h[idx] = acc;
}

// ---------------- CSR build: hist -> 3-phase scan -> scatter ----------------

__global__ void hist_kernel(const int* __restrict__ ei, int* __restrict__ deg, int E){
  int e = blockIdx.x*256 + threadIdx.x;
  if (e >= E) return;
  atomicAdd(&deg[ei[E + e]], 1);
}

__global__ void scan_partial(const int* __restrict__ deg, int* __restrict__ bsum, int N){
  int t = threadIdx.x;
  int i = blockIdx.x*256 + t;
  int v = (i < N) ? deg[i] : 0;
  #pragma unroll
  for (int m=32;m;m>>=1) v += __shfl_xor(v, m, 64);
  __shared__ int ws[4];
  if ((t & 63) == 0) ws[t>>6] = v;
  __syncthreads();
  if (t == 0) bsum[blockIdx.x] = ws[0]+ws[1]+ws[2]+ws[3];
}

__global__ void scan_bsum(int* __restrict__ bsum, int nb){
  __shared__ int sm[256];
  int t = threadIdx.x;
  int v = (t < nb) ? bsum[t] : 0;
  sm[t] = v; __syncthreads();
  #pragma unroll
  for (int off=1; off<256; off<<=1){
    int add = (t >= off) ? sm[t-off] : 0;
    __syncthreads();
    sm[t] += add;
    __syncthreads();
  }
  if (t < nb) bsum[t] = sm[t] - v;
}

__global__ void scan_write(const int* __restrict__ deg, const int* __restrict__ bsum,
                           int* __restrict__ rowptr, int* __restrict__ cursor, int N, int E){
  __shared__ int sm[256];
  int t = threadIdx.x;
  int i = blockIdx.x*256 + t;
  int v = (i < N) ? deg[i] : 0;
  sm[t] = v; __syncthreads();
  #pragma unroll
  for (int off=1; off<256; off<<=1){
    int add = (t >= off) ? sm[t-off] : 0;
    __syncthreads();
    sm[t] += add;
    __syncthreads();
  }
  if (i < N){
    int ex = bsum[blockIdx.x] + sm[t] - v;
    rowptr[i] = ex; cursor[i] = ex;
  }
  if (i == 0) rowptr[N] = E;
}

// Scatter edges into CSR order as packed {src*256, bin<<16 | f16(lerp_w)}.
__global__ void scatter_kernel(const int* __restrict__ ei, const float* __restrict__ dist,
                               int* __restrict__ cursor, int2* __restrict__ edata, int E){
  int e = blockIdx.x*256 + threadIdx.x;
  if (e >= E) return;
  int dst = ei[E + e];
  int pos = atomicAdd(&cursor[dst], 1);
  float d = dist[e];
  float xx = d * ((float)(NBINS-1) / 8.0f);
  int b = (int)xx;
  if (b > NBINS-2) b = NBINS-2;
  if (b < 0) b = 0;
  _Float16 hw = (_Float16)(xx - (float)b);
  unsigned short hb; __builtin_memcpy(&hb, &hw, 2);
  edata[pos] = make_int2(ei[e]*256, (b << 16) | (int)hb);
}

// ---------------- per-layer kernels ----------------

// MFMA node GEMM: [N,128]x[128,512] -> Pdst f16 [N][64][4] packed (+bias),
// Psrc f16 [N][64][4] packed. Packed p = 4*f' + {f_lo, s_lo, f_hi, s_hi}.
__launch_bounds__(256)
__global__ void node_gemm_kernel(const float* __restrict__ h, const _Float16* __restrict__ Wm,
                                 const float* __restrict__ Bias2, _Float16* __restrict__ Pdst,
                                 _Float16* __restrict__ Psrc, int N){
  int lane = threadIdx.x & 63;
  int w    = threadIdx.x >> 6;
  int m0   = blockIdx.x * 16;
  int arow = m0 + (lane & 15);
  int kbase= (lane >> 4) * 8;
  floatx4 acc[8];
  #pragma unroll
  for (int t=0;t<8;t++) acc[t] = (floatx4){0.f,0.f,0.f,0.f};
  #pragma unroll
  for (int kb=0; kb<4; kb++){
    const float* ap = h + arow*HID + kb*32 + kbase;
    float4 a0 = *(const float4*)ap;
    float4 a1 = *(const float4*)(ap+4);
    half8 af;
    af[0]=(_Float16)a0.x; af[1]=(_Float16)a0.y; af[2]=(_Float16)a0.z; af[3]=(_Float16)a0.w;
    af[4]=(_Float16)a1.x; af[5]=(_Float16)a1.y; af[6]=(_Float16)a1.z; af[7]=(_Float16)a1.w;
    const _Float16* bp = Wm + ((kb*32 + w*8)*64 + lane)*8;
    #pragma unroll
    for (int t=0;t<8;t++){
      half8 b8 = *(const half8*)(bp + t*512);
      acc[t] = __builtin_amdgcn_mfma_f32_16x16x32_f16(af, b8, acc[t], 0,0,0);
    }
  }
  int quad = lane >> 4;
  int cl   = lane & 15;
  int hi2  = (w & 1) ? 2 : 0;
  if (w < 2){
    #pragma unroll
    for (int t=0;t<8;t++){
      int cp = t*16 + cl;
      int c  = (w&1)*128 + cp;
      int p  = ((cp >> 1) << 2) + hi2 + (cp & 1);
      float b2 = Bias2[c];
      #pragma unroll
      for (int r=0;r<4;r++)
        Pdst[(m0 + quad*4 + r)*256 + p] = (_Float16)(acc[t][r] + b2);
    }
  } else {
    #pragma unroll
    for (int t=0;t<8;t++){
      int cp = t*16 + cl;
      int p  = ((cp >> 1) << 2) + hi2 + (cp & 1);
      #pragma unroll
      for (int r=0;r<4;r++)
        Psrc[(m0 + quad*4 + r)*256 + p] = (_Float16)acc[t][r];
    }
  }
}

// Aggregation: ONE WAVE PER NODE, lane owns features (f', f'+64) packed ×4.
// Table-lerp for RBF projection. No LDS, no barriers, max wave supply.
__launch_bounds__(256)
__global__ void agg_kernel(const _Float16* __restrict__ Pdst, const _Float16* __restrict__ Psrc,
                           const int2* __restrict__ edata, const int* __restrict__ rowptr,
                           const _Float16* __restrict__ T,
                           float2* __restrict__ agg2, float* __restrict__ bnstat){
  if (blockIdx.x == 0) bnstat[threadIdx.x] = 0.f;   // zero stats for bnstats_kernel
  int lane = threadIdx.x & 63;
  int w    = threadIdx.x >> 6;
  int l4   = lane * 4;
  int node = blockIdx.x*4 + w;
  half4t ad4 = *(const half4t*)(Pdst + node*256 + l4);
  float adx = (float)ad4[0], ady = (float)ad4[1], adz = (float)ad4[2], adw = (float)ad4[3];
  float acc0 = 0.f, acc1 = 0.f;
  int beg = rowptr[node], end = rowptr[node+1];
  #pragma unroll 4
  for (int j=beg; j<end; j++){
    int2 ed = edata[j];
    half4t p4 = *(const half4t*)(Psrc + ed.x + l4);
    int bin = ((unsigned)ed.y) >> 16;
    unsigned short hb = (unsigned short)(ed.y & 0xffff);
    _Float16 hw; __builtin_memcpy(&hw, &hb, 2);
    const _Float16* tp = T + bin*256 + l4;
    half4t t0 = *(const half4t*)tp;
    half4t t1 = *(const half4t*)(tp + 256);
    half4t res = t0 + (t1 - t0) * hw;
    float xf0 = adx + (float)p4[0] + (float)res[0];
    float xs0 = ady + (float)p4[1] + (float)res[1];
    float xf1 = adz + (float)p4[2] + (float)res[2];
    float xs1 = adw + (float)p4[3] + (float)res[3];
    float g0  = frcp(1.f + __expf(-xf0));
    float sp0 = fmaxf(xs0, 0.f) + __logf(1.f + __expf(-fabsf(xs0)));
    float g1  = frcp(1.f + __expf(-xf1));
    float sp1 = fmaxf(xs1, 0.f) + __logf(1.f + __expf(-fabsf(xs1)));
    acc0 += g0 * sp0;
    acc1 += g1 * sp1;
  }
  agg2[node*64 + lane] = make_float2(acc0, acc1);
}

// Column sums / sums-of-squares for BatchNorm batch stats (packed-col layout).
__global__ void bnstats_kernel(const float* __restrict__ agg, float* __restrict__ bnstat, int N){
  int f = threadIdx.x;  // 128 packed cols
  float s = 0.f, q = 0.f;
  for (int r = blockIdx.x; r < N; r += gridDim.x){
    float v = agg[r*HID + f];
    s += v; q += v*v;
  }
  atomicAdd(&bnstat[f],       s);
  atomicAdd(&bnstat[HID + f], q);
}

// Fused: BN-apply + residual + rowwise LayerNorm + ReLU + residual (in-place h).
// agg2 packed: lane holds features (lane, lane+64); stats packed (2lane, 2lane+1).
__global__ void apply_kernel(const float2* __restrict__ agg2, float* __restrict__ h,
                             const float* __restrict__ bnstat,
                             const float* __restrict__ bng, const float* __restrict__ bnb,
                             const float* __restrict__ lng, const float* __restrict__ lnb,
                             int N, float invN){
  int wave = threadIdx.x >> 6, lane = threadIdx.x & 63;
  int row = blockIdx.x*4 + wave;
  if (row >= N) return;
  int f0 = lane, f1 = lane + 64;
  float mu0 = bnstat[2*lane]*invN,   mu1 = bnstat[2*lane+1]*invN;
  float v0  = bnstat[HID+2*lane]*invN   - mu0*mu0;
  float v1  = bnstat[HID+2*lane+1]*invN - mu1*mu1;
  float2 a  = agg2[row*64 + lane];
  float h0 = h[row*HID + f0],   h1 = h[row*HID + f1];
  float c0 = (a.x-mu0)*rsqrtf(v0+LN_EPS)*bng[f0] + bnb[f0] + h0;
  float c1 = (a.y-mu1)*rsqrtf(v1+LN_EPS)*bng[f1] + bnb[f1] + h1;
  float s = c0 + c1, q = c0*c0 + c1*c1;
  #pragma unroll
  for (int m=32;m;m>>=1){ s += __shfl_xor(s,m,64); q += __shfl_xor(q,m,64); }
  float mean = s*(1.0f/128.0f);
  float var  = q*(1.0f/128.0f) - mean*mean;
  float r = rsqrtf(var + LN_EPS);
  float l0 = (c0-mean)*r*lng[f0] + lnb[f0];
  float l1 = (c1-mean)*r*lng[f1] + lnb[f1];
  h[row*HID + f0] = fmaxf(l0,0.f) + h0;
  h[row*HID + f1] = fmaxf(l1,0.f) + h1;
}

// Fused final LayerNorm + FC: 16 rows per 256-thread block via LDS.
__launch_bounds__(256)
__global__ void lnfc_kernel(const float* __restrict__ h,
                            const float* __restrict__ g, const float* __restrict__ b,
                            const float* __restrict__ Wfc, const float* __restrict__ bfc,
                            float* __restrict__ out, int N){
  __shared__ float sh[16][HID];
  __shared__ float wl[HID*NCLS];
  __shared__ float bl[NCLS];
  int t = threadIdx.x;
  for (int i = t; i < HID*NCLS; i += 256) wl[i] = Wfc[i];
  if (t < NCLS) bl[t] = bfc[t];
  int wave = t >> 6, lane = t & 63;
  int row0 = blockIdx.x*16;
  for (int i=0;i<4;i++){
    int rr  = wave*4 + i;
    int row = row0 + rr;
    if (row < N){
      float c0 = h[row*HID + lane], c1 = h[row*HID + lane + 64];
      float s = c0 + c1, q = c0*c0 + c1*c1;
      #pragma unroll
      for (int m=32;m;m>>=1){ s += __shfl_xor(s,m,64); q += __shfl_xor(q,m,64); }
      float mean = s*(1.0f/128.0f);
      float var  = q*(1.0f/128.0f) - mean*mean;
      float r = rsqrtf(var + LN_EPS);
      sh[rr][lane]      = (c0-mean)*r*g[lane]      + b[lane];
      sh[rr][lane + 64] = (c1-mean)*r*g[lane + 64] + b[lane + 64];
    }
  }
  __syncthreads();
  for (int idx = t; idx < 16*NCLS; idx += 256){
    int r = idx / NCLS, c = idx - r*NCLS;
    int orow = row0 + r;
    if (orow < N){
      float acc = bl[c];
      #pragma unroll 4
      for (int k=0;k<HID;k++) acc += sh[r][k]*wl[k*NCLS + c];
      out[orow*NCLS + c] = acc;
    }
  }
}

// ---------------- host launcher ----------------

extern "C" void kernel_launch(void* const* d_in, const int* in_sizes, int n_in,
                              void* d_out, int out_size, void* d_ws, size_t ws_size,
                              hipStream_t stream){
  const float* x    = (const float*)d_in[0];
  const int*   ei   = (const int*)  d_in[1];
  const float* dist = (const float*)d_in[2];
  const float* Wn   = (const float*)d_in[3];
  const float* bn   = (const float*)d_in[4];
  const float* Wf   = (const float*)d_in[5];
  const float* bf   = (const float*)d_in[6];
  const float* Ws   = (const float*)d_in[7];
  const float* bs   = (const float*)d_in[8];
  const float* bng  = (const float*)d_in[9];
  const float* bnb  = (const float*)d_in[10];
  const float* lng  = (const float*)d_in[11];
  const float* lnb  = (const float*)d_in[12];
  const float* lnog = (const float*)d_in[13];
  const float* lnob = (const float*)d_in[14];
  const float* Wfc  = (const float*)d_in[15];
  const float* bfc  = (const float*)d_in[16];
  float* out = (float*)d_out;

  const int N = in_sizes[0] / 6;     // 20000
  const int E = in_sizes[2];         // 320000
  const int NB = (N + 255)/256;

  char* p = (char*)d_ws;
  auto alloc = [&](size_t bytes)->void*{
    void* r = (void*)p;
    p += (bytes + 255) & ~(size_t)255;
    return r;
  };
  float*     h      = (float*)    alloc((size_t)N*HID*4);      // 10.24 MB
  _Float16*  Pdst   = (_Float16*) alloc((size_t)N*256*2);      // 10.24 MB
  _Float16*  Psrc   = (_Float16*) alloc((size_t)N*256*2);      // 10.24 MB
  float2*    agg2   = (float2*)   alloc((size_t)N*64*8);       // 10.24 MB
  _Float16*  Wm16   = (_Float16*) alloc((size_t)4*65536*2);    // 512 KB
  float*     Bias2  = (float*)    alloc((size_t)4*256*4);
  _Float16*  T      = (_Float16*) alloc((size_t)4*NBINS*256*2);// 2 MB
  float*     bnstat = (float*)    alloc((size_t)256*4);
  int*       deg    = (int*)      alloc((size_t)N*4);
  int*       rowptr = (int*)      alloc((size_t)(N+1)*4);
  int*       cursor = (int*)      alloc((size_t)N*4);
  int*       bsum   = (int*)      alloc((size_t)NB*4);
  int2*      edata  = (int2*)     alloc((size_t)E*8);          // 2.56 MB

  hipMemsetAsync(deg, 0, (size_t)N*4, stream);
  pack_kernel<<<1024, 256, 0, stream>>>(Wf, Ws, bf, bs, Wm16, Bias2);
  table_kernel<<<4*64, 256, 0, stream>>>(Wf, Ws, T);
  embed_kernel<<<(N*HID + 255)/256, 256, 0, stream>>>(x, Wn, bn, h, N);
  hist_kernel<<<(E + 255)/256, 256, 0, stream>>>(ei, deg, E);
  scan_partial<<<NB, 256, 0, stream>>>(deg, bsum, N);
  scan_bsum<<<1, 256, 0, stream>>>(bsum, NB);
  scan_write<<<NB, 256, 0, stream>>>(deg, bsum, rowptr, cursor, N, E);
  scatter_kernel<<<(E + 255)/256, 256, 0, stream>>>(ei, dist, cursor, edata, E);

  float invN = 1.0f / (float)N;
  for (int l = 0; l < 4; l++){
    node_gemm_kernel<<<N/16, 256, 0, stream>>>(
        h, Wm16 + (size_t)l*65536, Bias2 + (size_t)l*256, Pdst, Psrc, N);
    agg_kernel<<<N/4, 256, 0, stream>>>(
        Pdst, Psrc, edata, rowptr, T + (size_t)l*NBINS*256, agg2, bnstat);
    bnstats_kernel<<<1024, 128, 0, stream>>>((const float*)agg2, bnstat, N);
    apply_kernel<<<(N + 3)/4, 256, 0, stream>>>(
        agg2, h, bnstat, bng + l*HID, bnb + l*HID, lng + l*HID, lnb + l*HID, N, invN);
  }

  lnfc_kernel<<<(N + 15)/16, 256, 0, stream>>>(h, lnog, lnob, Wfc, bfc, out, N);
}